// Round 3
// baseline (334.703 us; speedup 1.0000x reference)
//
#include <hip/hip_runtime.h>
#include <math.h>

#define BATCH 32768
#define LW    200
#define CIN   6
#define KSZ   5
#define FLAT  196     // LW - KSZ + 1
#define NH1   50
#define NH2   30
#define NOUT  15

// Round-9: TWO-KERNEL SPLIT. Round-8 exposed the real bottleneck: with
// multi-wave blocks the compiler capped VGPRs at 68 (< h1p[50]+acc[28] live
// in fc1, << ~130 live in the Jacobi tail) -> scratch spills (hidden in L2),
// and the wave-0-only tail ran at 2 waves/CU for ~2/3 of wall time
// (occupancy-average arithmetic: 17.5% avg vs 43.75% main-phase ceiling).
//
// K1: conv + fc1 partial, 1-wave blocks (no barriers, no tail, no compiler
//     occupancy heuristics fighting us), __launch_bounds__(64,4) -> 128-VGPR
//     cap, ~90 live -> no spill. 7-way k-split -> 3584 blocks; XCD-chunked
//     bid remap puts all 7 slices of one batch-group on one XCD (x re-reads
//     become that XCD's L2 hits). Partials -> d_ws[s][j][b] (coalesced W+R).
// K2: per-batch reduce + fc2/fc3/Jacobi, 512 blocks x 64, one lane per
//     batch, free register budget (cap 256) -> no spill, and the tail runs
//     on ALL waves concurrently instead of 1 wave per 448-thread block.
// ws_size guard: 7-split needs 45.9 MB; falls back 4-split (26.2) / 2-split.

// ---------------- K1: conv1d + fc1 partials ----------------
// NS: conv outputs per slice; TB: tile base stride (off = (NS-TB)*s <= 3);
// COLS: staged cols; NLD: float4 loads/lane/channel; TW: LDS row stride (odd).
template<int NS, int TB, int COLS, int NLD, int TW, int NSPLIT, int MINW>
__global__ __launch_bounds__(64, MINW) void conv_fc1_kernel(
    const float* __restrict__ x,
    const float* __restrict__ cw, const float* __restrict__ cb,
    const float* __restrict__ w1,
    float* __restrict__ part)
{
    __shared__ float tile[64 * TW];

    const int lane = threadIdx.x;
    const int bid  = blockIdx.x;
    // XCD-chunked remap: hardware assigns XCD = bid & 7 (round-robin).
    // Give XCD r the batch-groups [64r, 64r+64); its NSPLIT slice-blocks per
    // group are consecutive in q -> x slab (300 KB) is fetched once into r's
    // L2 and re-read NSPLIT-1 times as L2 hits.
    const int r = bid & 7;
    const int q = bid >> 3;               // 0 .. 64*NSPLIT-1
    const int g = r * 64 + q / NSPLIT;    // batch group (64 batches)
    const int s = q - (q / NSPLIT) * NSPLIT;

    const int kstart = NS * s;            // conv-output slice [kstart, kstart+NS)
    const int tbase  = TB * s;            // 16B-aligned tile base col
    const int off    = kstart - tbase;    // window offset in tile (0..3)

    // conv weights / bias: uniform -> scalar regs
    float w[CIN][KSZ];
#pragma unroll
    for (int c = 0; c < CIN; ++c)
#pragma unroll
        for (int k = 0; k < KSZ; ++k) w[c][k] = cw[c * KSZ + k];
    const float bias = cb[0];

    // staging descriptors: float4 #g4 = lane + 64u of the [64 rows][NLD f4] tile
    int goff[NLD];
    int loff[NLD];
#pragma unroll
    for (int u = 0; u < NLD; ++u) {
        int g4  = lane + 64 * u;
        int row = g4 / NLD;               // pow2 or magic-div (compile-time)
        int c4  = g4 - row * NLD;
        goff[u] = row * (CIN * LW) + 4 * c4;
        loff[u] = row * TW + 4 * c4;
    }
    const float* xw = x + (size_t)g * 64 * (CIN * LW) + tbase;

    float acc[NS];
#pragma unroll
    for (int i = 0; i < NS; ++i) acc[i] = bias;

    // prologue: issue channel 0 loads (NLD independent dwordx4)
    float4 buf[NLD];
#pragma unroll
    for (int u = 0; u < NLD; ++u)
        buf[u] = *(const float4*)(xw + goff[u]);

#pragma unroll
    for (int ch = 0; ch < CIN; ++ch) {
        // drain buf -> LDS (wave-internal, in-order; no barrier needed)
#pragma unroll
        for (int u = 0; u < NLD; ++u) {
            float* dst = tile + loff[u];
            dst[0] = buf[u].x; dst[1] = buf[u].y; dst[2] = buf[u].z; dst[3] = buf[u].w;
        }
        // issue next channel's loads before consuming this one (hide latency)
        if (ch + 1 < CIN) {
#pragma unroll
            for (int u = 0; u < NLD; ++u)
                buf[u] = *(const float4*)(xw + (ch + 1) * LW + goff[u]);
        }
        // conv accumulate (batch = lane); odd TW -> conflict-free
        const float* row = tile + lane * TW + off;
        float x0 = row[0], x1 = row[1], x2 = row[2], x3 = row[3];
#pragma unroll
        for (int i = 0; i < NS; ++i) {
            float x4v = row[i + 4];
            float a = acc[i];
            a = fmaf(x0, w[ch][0], a);
            a = fmaf(x1, w[ch][1], a);
            a = fmaf(x2, w[ch][2], a);
            a = fmaf(x3, w[ch][3], a);
            a = fmaf(x4v, w[ch][4], a);
            acc[i] = a;
            x0 = x1; x1 = x2; x2 = x3; x3 = x4v;
        }
    }

    // fc1 partials: rows kstart..kstart+NS-1 of w1 (wave-uniform -> s_load)
    float h1p[NH1];
#pragma unroll
    for (int j = 0; j < NH1; ++j) h1p[j] = 0.f;
#pragma unroll
    for (int ii = 0; ii < NS; ++ii) {
        const float* wrow = w1 + (size_t)(kstart + ii) * NH1;
        float c = acc[ii];
#pragma unroll
        for (int j = 0; j < NH1; ++j) h1p[j] = fmaf(c, wrow[j], h1p[j]);
    }

    // store partials: part[(s*NH1 + j)*BATCH + b] -- lane-contiguous (coalesced)
    float* pb = part + (size_t)(s * NH1) * BATCH + (size_t)g * 64 + lane;
#pragma unroll
    for (int j = 0; j < NH1; ++j)
        pb[(size_t)j * BATCH] = h1p[j];
}

// ---------------- K2: reduce + fc2 + fc3 + Procrustes ----------------
template<int NSPLIT>
__global__ __launch_bounds__(64, 2) void tail_kernel(
    const float* __restrict__ part,
    const float* __restrict__ b1,
    const float* __restrict__ w2, const float* __restrict__ b2,
    const float* __restrict__ w3, const float* __restrict__ b3,
    float* __restrict__ out)
{
    const int bid = blockIdx.x;
    const int g   = (bid & 7) * 64 + (bid >> 3);   // same XCD chunking as K1
    const int b   = g * 64 + threadIdx.x;

    // h1 = relu(b1 + sum_s partial_s)   (coalesced loads across lanes)
    float h1[NH1];
#pragma unroll
    for (int j = 0; j < NH1; ++j) {
        float a = b1[j];
#pragma unroll
        for (int s = 0; s < NSPLIT; ++s)
            a += part[(size_t)(s * NH1 + j) * BATCH + b];
        h1[j] = fmaxf(a, 0.f);
    }

    // fc2
    float h2[NH2];
#pragma unroll
    for (int j = 0; j < NH2; ++j) h2[j] = b2[j];
#pragma unroll
    for (int k = 0; k < NH1; ++k) {
        float hk = h1[k];
        const float* row = w2 + k * NH2;              // uniform -> s_load
#pragma unroll
        for (int j = 0; j < NH2; ++j) h2[j] = fmaf(hk, row[j], h2[j]);
    }
#pragma unroll
    for (int j = 0; j < NH2; ++j) h2[j] = fmaxf(h2[j], 0.f);

    // fc3 (no relu)
    float o[NOUT];
#pragma unroll
    for (int j = 0; j < NOUT; ++j) o[j] = b3[j];
#pragma unroll
    for (int k = 0; k < NH2; ++k) {
        float hk = h2[k];
        const float* row = w3 + k * NOUT;             // uniform -> s_load
#pragma unroll
        for (int j = 0; j < NOUT; ++j) o[j] = fmaf(hk, row[j], o[j]);
    }

    // ---- closest proper rotation (Davenport K-matrix, f32 Jacobi) ----
    float r00 = o[0], r01 = o[1], r02 = o[2];
    float r10 = o[3], r11 = o[4], r12 = o[5];
    float r20 = o[6], r21 = o[7], r22 = o[8];

    float A[4][4], V[4][4];
    A[0][0] = r00 + r11 + r22;
    A[1][1] = r00 - r11 - r22;
    A[2][2] = r11 - r00 - r22;
    A[3][3] = r22 - r00 - r11;
    A[0][1] = A[1][0] = r21 - r12;
    A[0][2] = A[2][0] = r02 - r20;
    A[0][3] = A[3][0] = r10 - r01;
    A[1][2] = A[2][1] = r01 + r10;
    A[1][3] = A[3][1] = r02 + r20;
    A[2][3] = A[3][2] = r12 + r21;
#pragma unroll
    for (int i = 0; i < 4; ++i)
#pragma unroll
        for (int j = 0; j < 4; ++j) V[i][j] = (i == j) ? 1.f : 0.f;

    const int pr[6][2] = {{0,1},{0,2},{0,3},{1,2},{1,3},{2,3}};
    for (int sweep = 0; sweep < 7; ++sweep) {
#pragma unroll
        for (int pi = 0; pi < 6; ++pi) {
            const int p = pr[pi][0], qq = pr[pi][1];
            float apq = A[p][qq];
            if (fabsf(apq) > 1e-20f) {
                float theta = (A[qq][qq] - A[p][p]) / (2.f * apq);
                float t = copysignf(1.f, theta) / (fabsf(theta) + sqrtf(1.f + theta * theta));
                float c = rsqrtf(1.f + t * t);
                float sn = t * c;
#pragma unroll
                for (int k = 0; k < 4; ++k) {
                    float akp = A[k][p], akq = A[k][qq];
                    A[k][p] = c * akp - sn * akq;
                    A[k][qq] = sn * akp + c * akq;
                }
#pragma unroll
                for (int k = 0; k < 4; ++k) {
                    float apk = A[p][k], aqk = A[qq][k];
                    A[p][k] = c * apk - sn * aqk;
                    A[qq][k] = sn * apk + c * aqk;
                }
#pragma unroll
                for (int k = 0; k < 4; ++k) {
                    float vkp = V[k][p], vkq = V[k][qq];
                    V[k][p] = c * vkp - sn * vkq;
                    V[k][qq] = sn * vkp + c * vkq;
                }
            }
        }
    }

    int best = 0;
    float bl = A[0][0];
#pragma unroll
    for (int i = 1; i < 4; ++i)
        if (A[i][i] > bl) { bl = A[i][i]; best = i; }

    float vw = V[0][best], vx = V[1][best], vy = V[2][best], vz = V[3][best];
    float inv = rsqrtf(vw * vw + vx * vx + vy * vy + vz * vz);
    vw *= inv; vx *= inv; vy *= inv; vz *= inv;

    float xx = vx * vx, yy = vy * vy, zz = vz * vz;
    float xy = vx * vy, xz = vx * vz, yz = vy * vz;
    float wx = vw * vx, wy = vw * vy, wz = vw * vz;

    float* ob = out + (long)b * NOUT;
    ob[0]  = 1.f - 2.f * (yy + zz);
    ob[1]  = 2.f * (xy - wz);
    ob[2]  = 2.f * (xz + wy);
    ob[3]  = 2.f * (xy + wz);
    ob[4]  = 1.f - 2.f * (xx + zz);
    ob[5]  = 2.f * (yz - wx);
    ob[6]  = 2.f * (xz - wy);
    ob[7]  = 2.f * (yz + wx);
    ob[8]  = 1.f - 2.f * (xx + yy);
    ob[9]  = o[9];
    ob[10] = o[10];
    ob[11] = o[11];
    ob[12] = o[12];
    ob[13] = o[13];
    ob[14] = o[14];
}

extern "C" void kernel_launch(void* const* d_in, const int* in_sizes, int n_in,
                              void* d_out, int out_size, void* d_ws, size_t ws_size,
                              hipStream_t stream) {
    const float* x  = (const float*)d_in[0];
    const float* cw = (const float*)d_in[1];
    const float* cb = (const float*)d_in[2];
    const float* w1 = (const float*)d_in[3];
    const float* b1 = (const float*)d_in[4];
    const float* w2 = (const float*)d_in[5];
    const float* b2 = (const float*)d_in[6];
    const float* w3 = (const float*)d_in[7];
    const float* b3 = (const float*)d_in[8];
    float* outp = (float*)d_out;
    float* part = (float*)d_ws;

    const size_t need7 = (size_t)7 * NH1 * BATCH * sizeof(float);  // 45.9 MB
    const size_t need4 = (size_t)4 * NH1 * BATCH * sizeof(float);  // 26.2 MB

    if (ws_size >= need7) {
        // NS=28, TB=28 (off=0), COLS=32, NLD=8, TW=33, 7 slices, VGPR cap 128
        conv_fc1_kernel<28, 28, 32, 8, 33, 7, 4>
            <<<7 * (BATCH / 64), 64, 0, stream>>>(x, cw, cb, w1, part);
        tail_kernel<7><<<BATCH / 64, 64, 0, stream>>>(part, b1, w2, b2, w3, b3, outp);
    } else if (ws_size >= need4) {
        // NS=49, TB=48 (off=s), COLS=56, NLD=14, TW=57, 4 slices, VGPR cap 170
        conv_fc1_kernel<49, 48, 56, 14, 57, 4, 3>
            <<<4 * (BATCH / 64), 64, 0, stream>>>(x, cw, cb, w1, part);
        tail_kernel<4><<<BATCH / 64, 64, 0, stream>>>(part, b1, w2, b2, w3, b3, outp);
    } else {
        // NS=98, TB=96 (off=2s), COLS=104, NLD=26, TW=105, 2 slices, cap 256
        conv_fc1_kernel<98, 96, 104, 26, 105, 2, 1>
            <<<2 * (BATCH / 64), 64, 0, stream>>>(x, cw, cb, w1, part);
        tail_kernel<2><<<BATCH / 64, 64, 0, stream>>>(part, b1, w2, b2, w3, b3, outp);
    }
}